// Round 7
// baseline (29.368 us; speedup 1.0000x reference)
//
#include <hip/hip_runtime.h>

// Masked normalized cross-correlation, b=8, c=1, H=W=128, p=9.
// R6: overhead A/B test. R1-R5 invariance (17.2-19.3 us across radically
// different internals) points at fixed per-node graph overhead (2 kernel
// nodes + dependency). This round: single kernel node (+32B memset);
// cross-block reduction via one f32 atomicAdd per block (TCC pipelines
// same-line atomics; R0 proved atomics+memset pass validation).
// Internals = R1's best-known structure; inner loop flat-element unrolled
// with compile-time (r,c) offsets.

#define BATCH 8
#define HH    128
#define WW    128
#define PP    9
#define HP    120
#define WP    120
#define NPATCH (HP * WP)        // 14400
#define PSQ   (PP * PP)         // 81
#define EPSF  1e-5f
#define SCALE (1.0f / ((float)NPATCH * (float)PSQ))

__device__ __forceinline__ void gload16(const void* g, void* lds) {
    __builtin_amdgcn_global_load_lds(
        (const __attribute__((address_space(1))) void*)g,
        (__attribute__((address_space(3))) void*)lds, 16, 0, 0);
}

__global__ __launch_bounds__(256) void ncc_kernel(const float* __restrict__ x1,
                                                  const float* __restrict__ x2,
                                                  const float* __restrict__ mask,
                                                  float* __restrict__ out)
{
    const int blk  = blockIdx.x;          // 0 .. 959
    const int b    = blk / HP;
    const int i    = blk - b * HP;        // patch row
    const int tid  = threadIdx.x;
    const int lane = tid & 63;

    __shared__ __align__(16) float m_lds[WP * PSQ];   // 9720 f = 38880 B
    __shared__ __align__(16) float x_lds[2][PP * WW]; // 2*1152 f = 9216 B
    __shared__ float wsum[4];

    // ---- stage mask row: 2430 float4, direct global->LDS ----
    {
        const float4* msrc = reinterpret_cast<const float4*>(
            mask + ((size_t)b * NPATCH + (size_t)i * WP) * PSQ);
        char* mdst = reinterpret_cast<char*>(m_lds);
        #pragma unroll
        for (int k = 0; k < 10; ++k) {
            int t = k * 256 + tid;
            if (t < (WP * PSQ) / 4)                    // 2430
                gload16(msrc + t, mdst + (size_t)(t - lane) * 16);
        }
    }
    // ---- stage x1/x2 rows i..i+8 (288 float4 each) ----
    {
        const float4* s1 = reinterpret_cast<const float4*>(x1 + ((size_t)(b * HH + i)) * WW);
        const float4* s2 = reinterpret_cast<const float4*>(x2 + ((size_t)(b * HH + i)) * WW);
        char* d1 = reinterpret_cast<char*>(&x_lds[0][0]);
        char* d2 = reinterpret_cast<char*>(&x_lds[1][0]);
        #pragma unroll
        for (int k = 0; k < 2; ++k) {
            int t = k * 256 + tid;
            if (t < (PP * WW) / 4) {                   // 288
                gload16(s1 + t, d1 + (size_t)(t - lane) * 16);
                gload16(s2 + t, d2 + (size_t)(t - lane) * 16);
            }
        }
    }
    __syncthreads();   // drains vmcnt(0): all LDS buffers ready

    // ---- compute: 2 lanes per patch, flat elements 0..44 / 45..80 ----
    float val = 0.0f;
    const int j = tid >> 1;      // patch column
    const int h = tid & 1;       // element-half selector
    if (j < WP) {
        const int n = 45 - 9 * h;                     // 45 or 36 live elems
        const float* mp = m_lds + j * PSQ + 45 * h;
        const float* xa = &x_lds[0][5 * h * WW + j];  // rows 5h + t/9
        const float* xb = &x_lds[1][5 * h * WW + j];
        float sa = 0.f, saa = 0.f, sb = 0.f, sbb = 0.f, sab = 0.f;
        #pragma unroll
        for (int t = 0; t < 45; ++t) {
            const int r = t / 9;                      // compile-time
            const int c = t - 9 * r;
            if (t < n) {
                float a  = xa[r * WW + c];
                float bv = xb[r * WW + c] * mp[t];
                sa += a;  saa = fmaf(a, a, saa);
                sb += bv; sbb = fmaf(bv, bv, sbb);
                sab = fmaf(a, bv, sab);
            }
        }
        sa  += __shfl_xor(sa, 1);
        saa += __shfl_xor(saa, 1);
        sb  += __shfl_xor(sb, 1);
        sbb += __shfl_xor(sbb, 1);
        sab += __shfl_xor(sab, 1);
        if (h == 0) {
            const float invN = 1.0f / 81.0f;
            float mua  = sa * invN;
            float mub  = sb * invN;
            float vara = saa * invN - mua * mua + EPSF;
            float varb = sbb * invN - mub * mub + EPSF;
            float cov  = sab - 81.0f * mua * mub;
            val = cov / sqrtf(vara * varb);
        }
    }

    // ---- block reduction -> one atomicAdd per block ----
    #pragma unroll
    for (int off = 32; off > 0; off >>= 1)
        val += __shfl_down(val, off);
    const int wave = tid >> 6;
    if ((tid & 63) == 0) wsum[wave] = val;
    __syncthreads();
    if (tid == 0)
        atomicAdd(out + b, (wsum[0] + wsum[1] + wsum[2] + wsum[3]) * SCALE);
}

extern "C" void kernel_launch(void* const* d_in, const int* in_sizes, int n_in,
                              void* d_out, int out_size, void* d_ws, size_t ws_size,
                              hipStream_t stream) {
    const float* x1   = (const float*)d_in[0];
    const float* x2   = (const float*)d_in[1];
    const float* mask = (const float*)d_in[2];
    float* out = (float*)d_out;

    hipMemsetAsync(out, 0, out_size * sizeof(float), stream);
    ncc_kernel<<<BATCH * HP, 256, 0, stream>>>(x1, x2, mask, out);
}

// Round 8
// 18.173 us; speedup vs baseline: 1.6161x; 1.6161x over previous
//
#include <hip/hip_runtime.h>

// Masked normalized cross-correlation, b=8, c=1, H=W=128, p=9.
// R7: DS-instruction cut. Per element the compute phase previously did
// 3x ds_read_b32 (x1, x2, m). Now a prep pass builds pk[(row)][col] =
// float4{x1, x2, x1*x2, 0} (16B-aligned for any col) so compute does
// 1x ds_read_b128 + 1x ds_read_b32(m), and sab = fma(x12, m).
// 480 blocks x 256t, each owns (batch, 2 patch-rows) serially; LDS
// 59.4 KB -> 2 blocks/CU, 480/512 co-resident -> no dispatch tail.
// Mask staged per row via global_load_lds (proven R1 path); x slab read
// straight from global (L2-resident, coalesced float4) during prep.

#define BATCH 8
#define HH    128
#define WW    128
#define PP    9
#define HP    120
#define WP    120
#define NPATCH (HP * WP)        // 14400
#define PSQ   (PP * PP)         // 81
#define EPSF  1e-5f
#define NBLK  (BATCH * HP / 2)  // 480

__device__ __forceinline__ void gload16(const void* g, void* lds) {
    __builtin_amdgcn_global_load_lds(
        (const __attribute__((address_space(1))) void*)g,
        (__attribute__((address_space(3))) void*)lds, 16, 0, 0);
}

__global__ __launch_bounds__(256) void ncc_kernel(const float* __restrict__ x1,
                                                  const float* __restrict__ x2,
                                                  const float* __restrict__ mask,
                                                  float* __restrict__ part)
{
    const int blk  = blockIdx.x;            // 0..479
    const int b    = blk / 60;
    const int i0   = (blk - b * 60) * 2;    // patch rows i0, i0+1
    const int tid  = threadIdx.x;
    const int lane = tid & 63;

    __shared__ __align__(16) float  m_lds[WP * PSQ];   // 9720 f = 38880 B
    __shared__ __align__(16) float4 pk[10 * WW];       // 1280 f4 = 20480 B
    __shared__ float wsum[4];

    // ---- issue mask row i0 staging (2430 float4, global->LDS direct) ----
    auto stage_mask = [&](int ri) {
        const float4* msrc = (const float4*)(
            mask + ((size_t)b * NPATCH + (size_t)ri * WP) * PSQ);
        char* mdst = (char*)m_lds;
        #pragma unroll
        for (int k = 0; k < 10; ++k) {
            int t = k * 256 + tid;
            if (t < (WP * PSQ) / 4)                    // 2430
                gload16(msrc + t, mdst + (size_t)(t - lane) * 16);
        }
    };
    stage_mask(i0);

    // ---- prep: build pk rows i0..i0+9 from global (coalesced float4) ----
    {
        const float4* s1 = (const float4*)(x1 + ((size_t)(b * HH + i0)) * WW);
        const float4* s2 = (const float4*)(x2 + ((size_t)(b * HH + i0)) * WW);
        #pragma unroll
        for (int k = 0; k < 2; ++k) {
            int t = k * 256 + tid;                     // float4 index, <320
            if (t < 320) {
                float4 a = s1[t];
                float4 c = s2[t];
                pk[t * 4 + 0] = make_float4(a.x, c.x, a.x * c.x, 0.f);
                pk[t * 4 + 1] = make_float4(a.y, c.y, a.y * c.y, 0.f);
                pk[t * 4 + 2] = make_float4(a.z, c.z, a.z * c.z, 0.f);
                pk[t * 4 + 3] = make_float4(a.w, c.w, a.w * c.w, 0.f);
            }
        }
    }

    float val = 0.0f;
    #pragma unroll
    for (int rr = 0; rr < 2; ++rr) {
        __syncthreads();                   // mask(i0+rr) + pk ready (vmcnt drained)

        const int j = tid >> 1;            // patch column 0..119
        const int h = tid & 1;             // element-half selector
        if (j < WP) {
            const int r0 = h ? 5 : 0;
            const int r1 = h ? 9 : 5;
            float sa = 0.f, saa = 0.f, sb = 0.f, sbb = 0.f, sab = 0.f;
            const float*  mp  = m_lds + j * PSQ + r0 * PP;
            const float4* pkb = &pk[(rr + r0) * WW + j];
            for (int r = r0; r < r1; ++r) {
                #pragma unroll
                for (int cc = 0; cc < PP; ++cc) {
                    float4 v = pkb[cc];            // ds_read_b128: x1,x2,x12
                    float  m = mp[cc];             // ds_read_b32
                    float  bv = v.y * m;
                    sa += v.x;  saa = fmaf(v.x, v.x, saa);
                    sb += bv;   sbb = fmaf(bv, bv, sbb);
                    sab = fmaf(v.z, m, sab);
                }
                mp  += PP;
                pkb += WW;
            }
            sa  += __shfl_xor(sa, 1);
            saa += __shfl_xor(saa, 1);
            sb  += __shfl_xor(sb, 1);
            sbb += __shfl_xor(sbb, 1);
            sab += __shfl_xor(sab, 1);
            if (h == 0) {
                const float invN = 1.0f / 81.0f;
                float mua  = sa * invN;
                float mub  = sb * invN;
                float vara = saa * invN - mua * mua + EPSF;
                float varb = sbb * invN - mub * mub + EPSF;
                float cov  = sab - 81.0f * mua * mub;
                val += cov / sqrtf(vara * varb);
            }
        }

        if (rr == 0) {
            __syncthreads();               // everyone done reading m_lds
            stage_mask(i0 + 1);            // restage same buffer for row 2
        }
    }

    // ---- block reduction (4 waves) -> one plain store ----
    #pragma unroll
    for (int off = 32; off > 0; off >>= 1)
        val += __shfl_down(val, off);
    if ((tid & 63) == 0) wsum[tid >> 6] = val;
    __syncthreads();
    if (tid == 0)
        part[blk] = wsum[0] + wsum[1] + wsum[2] + wsum[3];
}

__global__ __launch_bounds__(64) void finalize_kernel(const float* __restrict__ part,
                                                      float* __restrict__ out)
{
    const int b = blockIdx.x;       // 0..7
    const int t = threadIdx.x;      // 0..63
    float v = (t < 60) ? part[b * 60 + t] : 0.0f;
    #pragma unroll
    for (int off = 32; off > 0; off >>= 1)
        v += __shfl_down(v, off);
    if (t == 0)
        out[b] = v * (1.0f / ((float)NPATCH * (float)PSQ));
}

extern "C" void kernel_launch(void* const* d_in, const int* in_sizes, int n_in,
                              void* d_out, int out_size, void* d_ws, size_t ws_size,
                              hipStream_t stream) {
    const float* x1   = (const float*)d_in[0];
    const float* x2   = (const float*)d_in[1];
    const float* mask = (const float*)d_in[2];
    float* out  = (float*)d_out;
    float* part = (float*)d_ws;     // 480 floats of scratch

    ncc_kernel<<<NBLK, 256, 0, stream>>>(x1, x2, mask, part);
    finalize_kernel<<<BATCH, 64, 0, stream>>>(part, out);
}